// Round 1
// baseline (468.911 us; speedup 1.0000x reference)
//
#include <hip/hip_runtime.h>

// Maxwell RNN scan: gamma_n = (1-h_n) gamma_{n-1} + h_n eps_n, h = 0.5*dt
// sig_n = 2.5*eps_n - gamma_{n-1}   (pre-update gamma)
// Single-tile version: the whole 8192-element row is processed in ONE pass
// (512 threads x 16 elements), so gamma_in = 0 and there is no cross-tile
// carry, no block-total transform, and only ONE __syncthreads.

constexpr int   T_LEN   = 8192;
constexpr int   THREADS = 512;
constexpr int   V       = 16;             // elements per thread
constexpr int   NWAVES  = THREADS / 64;   // 8
constexpr float KCOEF   = 0.5f;           // E_MOD / ETA

typedef float f32x4 __attribute__((ext_vector_type(4)));

__global__ __launch_bounds__(THREADS, 8) void maxwell_scan_kernel(
    const float* __restrict__ eps, const float* __restrict__ dtv,
    float* __restrict__ out)
{
    const size_t row = (size_t)blockIdx.x * T_LEN;
    const float* e_row = eps + row;
    const float* d_row = dtv + row;
    float*       o_row = out + row;

    __shared__ float wA[NWAVES];
    __shared__ float wB[NWAVES];

    const int lane = threadIdx.x & 63;
    const int wid  = threadIdx.x >> 6;
    const int base = threadIdx.x * V;

    // ---- Load the thread's whole chunk: 4+4 x dwordx4, all issued up front.
    f32x4 e0 = *(const f32x4*)(e_row + base);
    f32x4 e1 = *(const f32x4*)(e_row + base + 4);
    f32x4 e2 = *(const f32x4*)(e_row + base + 8);
    f32x4 e3 = *(const f32x4*)(e_row + base + 12);
    f32x4 d0 = *(const f32x4*)(d_row + base);
    f32x4 d1 = *(const f32x4*)(d_row + base + 4);
    f32x4 d2 = *(const f32x4*)(d_row + base + 8);
    f32x4 d3 = *(const f32x4*)(d_row + base + 12);

    float ev[V] = {e0.x, e0.y, e0.z, e0.w, e1.x, e1.y, e1.z, e1.w,
                   e2.x, e2.y, e2.z, e2.w, e3.x, e3.y, e3.z, e3.w};
    float hv[V] = {d0.x * KCOEF, d0.y * KCOEF, d0.z * KCOEF, d0.w * KCOEF,
                   d1.x * KCOEF, d1.y * KCOEF, d1.z * KCOEF, d1.w * KCOEF,
                   d2.x * KCOEF, d2.y * KCOEF, d2.z * KCOEF, d2.w * KCOEF,
                   d3.x * KCOEF, d3.y * KCOEF, d3.z * KCOEF, d3.w * KCOEF};

    // ---- Compose this thread's chunk: gamma_out = A*gamma_in + Bc
    float A = 1.0f, Bc = 0.0f;
    #pragma unroll
    for (int j = 0; j < V; ++j) {
        float a = 1.0f - hv[j];
        Bc = a * Bc + hv[j] * ev[j];
        A  = a * A;
    }

    // ---- Inclusive wave scan under composition (later ∘ earlier).
    float sa = A, sb = Bc;
    #pragma unroll
    for (int off = 1; off < 64; off <<= 1) {
        float pa = __shfl_up(sa, off, 64);
        float pb = __shfl_up(sb, off, 64);
        if (lane >= off) {
            sb = sa * pb + sb;
            sa = sa * pa;
        }
    }
    if (lane == 63) { wA[wid] = sa; wB[wid] = sb; }
    __syncthreads();

    // ---- Exclusive-within-wave transform.
    float ea = __shfl_up(sa, 1, 64);
    float eb = __shfl_up(sb, 1, 64);
    if (lane == 0) { ea = 1.0f; eb = 0.0f; }

    // ---- B-prefix over preceding waves. gamma_in = 0 for the whole row,
    // so the A-prefix (pfa) and the block total are never needed.
    float pfb = 0.0f;
    for (int w = 0; w < wid; ++w) {          // wave-uniform loop bound
        pfb = wA[w] * pfb + wB[w];
    }

    // gamma entering this thread's chunk: apply (ea,eb) after the wave prefix
    // to gamma0 = 0  ->  g = ea*pfb + eb.
    float g = ea * pfb + eb;

    // ---- Replay chunk: emit sigma, advance gamma. Nontemporal stores keep
    // L2/L3 free for the (exactly L3-sized) inputs.
    #pragma unroll
    for (int q = 0; q < V / 4; ++q) {
        f32x4 s;
        #pragma unroll
        for (int j = 0; j < 4; ++j) {
            const int idx = q * 4 + j;
            s[j] = 2.5f * ev[idx] - g;            // E_INF*e + E*(e - g)
            g = g + hv[idx] * (ev[idx] - g);      // g += dt*k*(e - g)
        }
        __builtin_nontemporal_store(s, (f32x4*)(o_row + base + q * 4));
    }
}

extern "C" void kernel_launch(void* const* d_in, const int* in_sizes, int n_in,
                              void* d_out, int out_size, void* d_ws, size_t ws_size,
                              hipStream_t stream) {
    const float* eps = (const float*)d_in[0];
    const float* dtv = (const float*)d_in[1];
    float* out = (float*)d_out;
    const int B = in_sizes[0] / T_LEN;   // 4096 rows
    maxwell_scan_kernel<<<B, THREADS, 0, stream>>>(eps, dtv, out);
}

// Round 2
// 324.554 us; speedup vs baseline: 1.4448x; 1.4448x over previous
//
#include <hip/hip_runtime.h>

// Maxwell RNN scan: gamma_n = (1-h_n) gamma_{n-1} + h_n eps_n, h = 0.5*dt
// sig_n = 2.5*eps_n - gamma_{n-1}   (pre-update gamma)
//
// Single-pass, fully-coalesced layout: 1024 threads, each owns TWO chunks of
// 4 consecutive elements: chunk0 at [4*tid, 4*tid+4), chunk1 at
// [4096 + 4*tid, ...). Every global load/store instruction therefore has
// lane-stride exactly 16B (100% coalescing density, full HBM lines).
// gamma_0 = 0 for the whole row, so chunk0 needs only B-prefixes; chunk1 is
// seeded by chunk0's block-total B (tb0). One __syncthreads total.

constexpr int   T_LEN   = 8192;
constexpr int   THREADS = 1024;
constexpr int   NWAVES  = THREADS / 64;   // 16
constexpr int   HALF    = T_LEN / 2;      // 4096
constexpr float KCOEF   = 0.5f;           // E_MOD / ETA

typedef float f32x4 __attribute__((ext_vector_type(4)));

__global__ __launch_bounds__(THREADS, 8) void maxwell_scan_kernel(
    const float* __restrict__ eps, const float* __restrict__ dtv,
    float* __restrict__ out)
{
    const size_t row = (size_t)blockIdx.x * T_LEN;
    const float* e_row = eps + row;
    const float* d_row = dtv + row;
    float*       o_row = out + row;

    __shared__ float wA0[NWAVES], wB0[NWAVES], wA1[NWAVES], wB1[NWAVES];

    const int lane = threadIdx.x & 63;
    const int wid  = threadIdx.x >> 6;
    const int i0   = threadIdx.x * 4;         // chunk0: elements [i0, i0+4)
    const int i1   = HALF + threadIdx.x * 4;  // chunk1: elements [i1, i1+4)

    // ---- Fully-coalesced loads: lane-stride 16B, issued back-to-back.
    f32x4 e0 = *(const f32x4*)(e_row + i0);
    f32x4 e1 = *(const f32x4*)(e_row + i1);
    f32x4 d0 = *(const f32x4*)(d_row + i0);
    f32x4 d1 = *(const f32x4*)(d_row + i1);

    const f32x4 h0 = d0 * KCOEF;
    const f32x4 h1 = d1 * KCOEF;

    // ---- Compose each chunk: gamma_out = A*gamma_in + B (time order).
    float A0 = 1.0f, B0 = 0.0f, A1 = 1.0f, B1 = 0.0f;
    #pragma unroll
    for (int j = 0; j < 4; ++j) {
        float a0 = 1.0f - h0[j];
        B0 = a0 * B0 + h0[j] * e0[j];
        A0 *= a0;
        float a1 = 1.0f - h1[j];
        B1 = a1 * B1 + h1[j] * e1[j];
        A1 *= a1;
    }

    // ---- Inclusive wave scans (both chunk sequences) under composition.
    float s0a = A0, s0b = B0, s1a = A1, s1b = B1;
    #pragma unroll
    for (int off = 1; off < 64; off <<= 1) {
        float p0a = __shfl_up(s0a, off, 64);
        float p0b = __shfl_up(s0b, off, 64);
        float p1a = __shfl_up(s1a, off, 64);
        float p1b = __shfl_up(s1b, off, 64);
        if (lane >= off) {
            s0b = s0a * p0b + s0b;  s0a *= p0a;
            s1b = s1a * p1b + s1b;  s1a *= p1a;
        }
    }
    if (lane == 63) {
        wA0[wid] = s0a; wB0[wid] = s0b;
        wA1[wid] = s1a; wB1[wid] = s1b;
    }
    __syncthreads();

    // ---- Exclusive-within-wave transforms.
    float e0a = __shfl_up(s0a, 1, 64), e0b = __shfl_up(s0b, 1, 64);
    float e1a = __shfl_up(s1a, 1, 64), e1b = __shfl_up(s1b, 1, 64);
    if (lane == 0) { e0a = 1.0f; e0b = 0.0f; e1a = 1.0f; e1b = 0.0f; }

    // ---- Wave-level prefixes (wave-uniform loops, tiny).
    // chunk0: only the B-component of the prefix is needed (gamma_in = 0).
    float pf0b = 0.0f;
    for (int w = 0; w < wid; ++w) pf0b = wA0[w] * pf0b + wB0[w];

    // chunk0 block total, applied to 0 -> seeds chunk1.
    float tb0 = 0.0f;
    #pragma unroll
    for (int w = 0; w < NWAVES; ++w) tb0 = wA0[w] * tb0 + wB0[w];

    // chunk1: need (A,B) of the wave prefix to apply it to tb0.
    float pf1a = 1.0f, pf1b = 0.0f;
    for (int w = 0; w < wid; ++w) {
        pf1b = wA1[w] * pf1b + wB1[w];
        pf1a *= wA1[w];
    }

    // gamma entering each chunk.
    float g0 = e0a * pf0b + e0b;
    float g1 = e1a * (pf1a * tb0 + pf1b) + e1b;

    // ---- Replay chunks: emit sigma, advance gamma. Stores are full-line
    // dense per wave, so nontemporal is safe and keeps output out of L3.
    f32x4 sg0, sg1;
    #pragma unroll
    for (int j = 0; j < 4; ++j) {
        sg0[j] = 2.5f * e0[j] - g0;          // E_INF*e + E*(e - g)
        g0 = g0 + h0[j] * (e0[j] - g0);      // g += dt*k*(e - g)
    }
    #pragma unroll
    for (int j = 0; j < 4; ++j) {
        sg1[j] = 2.5f * e1[j] - g1;
        g1 = g1 + h1[j] * (e1[j] - g1);
    }
    __builtin_nontemporal_store(sg0, (f32x4*)(o_row + i0));
    __builtin_nontemporal_store(sg1, (f32x4*)(o_row + i1));
}

extern "C" void kernel_launch(void* const* d_in, const int* in_sizes, int n_in,
                              void* d_out, int out_size, void* d_ws, size_t ws_size,
                              hipStream_t stream) {
    const float* eps = (const float*)d_in[0];
    const float* dtv = (const float*)d_in[1];
    float* out = (float*)d_out;
    const int B = in_sizes[0] / T_LEN;   // 4096 rows
    maxwell_scan_kernel<<<B, THREADS, 0, stream>>>(eps, dtv, out);
}

// Round 3
// 308.973 us; speedup vs baseline: 1.5176x; 1.0504x over previous
//
#include <hip/hip_runtime.h>

// Maxwell RNN scan: gamma_n = (1-h_n) gamma_{n-1} + h_n eps_n, h = 0.5*dt
// sig_n = 2.5*eps_n - gamma_{n-1}   (pre-update gamma)
//
// Single-pass: 512 threads, each owns TWO 8-element chunks:
//   chunk0 = [8*tid, 8*tid+8), chunk1 = [4096 + 8*tid, ...)
// Whole 8192-element row in one pass => gamma_in = 0, one __syncthreads.
// Load/store pattern identical to the proven round-0 one (two f32x4 per
// chunk, 32B lane stride, pair covers full lines; plain stores — measured
// no HBM write amplification, unlike nontemporal which gave 1.5-2.6x).

constexpr int   T_LEN   = 8192;
constexpr int   THREADS = 512;
constexpr int   NWAVES  = THREADS / 64;   // 8
constexpr int   HALF    = T_LEN / 2;      // 4096
constexpr float KCOEF   = 0.5f;           // E_MOD / ETA

typedef float f32x4 __attribute__((ext_vector_type(4)));

__global__ __launch_bounds__(THREADS) void maxwell_scan_kernel(
    const float* __restrict__ eps, const float* __restrict__ dtv,
    float* __restrict__ out)
{
    const size_t row = (size_t)blockIdx.x * T_LEN;
    const float* e_row = eps + row;
    const float* d_row = dtv + row;
    float*       o_row = out + row;

    __shared__ float wA0[NWAVES], wB0[NWAVES], wA1[NWAVES], wB1[NWAVES];

    const int lane = threadIdx.x & 63;
    const int wid  = threadIdx.x >> 6;
    const int i0   = threadIdx.x * 8;         // chunk0
    const int i1   = HALF + threadIdx.x * 8;  // chunk1

    // ---- All 8 global loads issued up-front, back-to-back.
    f32x4 ev00 = *(const f32x4*)(e_row + i0);
    f32x4 ev01 = *(const f32x4*)(e_row + i0 + 4);
    f32x4 ev10 = *(const f32x4*)(e_row + i1);
    f32x4 ev11 = *(const f32x4*)(e_row + i1 + 4);
    f32x4 dv00 = *(const f32x4*)(d_row + i0);
    f32x4 dv01 = *(const f32x4*)(d_row + i0 + 4);
    f32x4 dv10 = *(const f32x4*)(d_row + i1);
    f32x4 dv11 = *(const f32x4*)(d_row + i1 + 4);

    float e0[8] = {ev00.x, ev00.y, ev00.z, ev00.w, ev01.x, ev01.y, ev01.z, ev01.w};
    float e1[8] = {ev10.x, ev10.y, ev10.z, ev10.w, ev11.x, ev11.y, ev11.z, ev11.w};
    float h0[8] = {dv00.x * KCOEF, dv00.y * KCOEF, dv00.z * KCOEF, dv00.w * KCOEF,
                   dv01.x * KCOEF, dv01.y * KCOEF, dv01.z * KCOEF, dv01.w * KCOEF};
    float h1[8] = {dv10.x * KCOEF, dv10.y * KCOEF, dv10.z * KCOEF, dv10.w * KCOEF,
                   dv11.x * KCOEF, dv11.y * KCOEF, dv11.z * KCOEF, dv11.w * KCOEF};

    // ---- Compose each chunk (time order): gamma_out = A*gamma_in + B.
    float A0 = 1.0f, B0 = 0.0f, A1 = 1.0f, B1 = 0.0f;
    #pragma unroll
    for (int j = 0; j < 8; ++j) {
        float a0 = 1.0f - h0[j];
        B0 = a0 * B0 + h0[j] * e0[j];
        A0 *= a0;
        float a1 = 1.0f - h1[j];
        B1 = a1 * B1 + h1[j] * e1[j];
        A1 *= a1;
    }

    // ---- Inclusive wave scans (both sequences) under composition.
    float s0a = A0, s0b = B0, s1a = A1, s1b = B1;
    #pragma unroll
    for (int off = 1; off < 64; off <<= 1) {
        float p0a = __shfl_up(s0a, off, 64);
        float p0b = __shfl_up(s0b, off, 64);
        float p1a = __shfl_up(s1a, off, 64);
        float p1b = __shfl_up(s1b, off, 64);
        if (lane >= off) {
            s0b = s0a * p0b + s0b;  s0a *= p0a;
            s1b = s1a * p1b + s1b;  s1a *= p1a;
        }
    }
    if (lane == 63) {
        wA0[wid] = s0a; wB0[wid] = s0b;
        wA1[wid] = s1a; wB1[wid] = s1b;
    }
    __syncthreads();

    // ---- Exclusive-within-wave transforms.
    float x0a = __shfl_up(s0a, 1, 64), x0b = __shfl_up(s0b, 1, 64);
    float x1a = __shfl_up(s1a, 1, 64), x1b = __shfl_up(s1b, 1, 64);
    if (lane == 0) { x0a = 1.0f; x0b = 0.0f; x1a = 1.0f; x1b = 0.0f; }

    // ---- Wave-level prefixes (wave-uniform, tiny).
    // chunk0: gamma_in = 0 -> only B-component of the prefix needed.
    float pf0b = 0.0f;
    for (int w = 0; w < wid; ++w) pf0b = wA0[w] * pf0b + wB0[w];

    // chunk0 block total applied to 0 -> seeds chunk1.
    float tb0 = 0.0f;
    #pragma unroll
    for (int w = 0; w < NWAVES; ++w) tb0 = wA0[w] * tb0 + wB0[w];

    // chunk1: full (A,B) prefix, applied to tb0.
    float pf1a = 1.0f, pf1b = 0.0f;
    for (int w = 0; w < wid; ++w) {
        pf1b = wA1[w] * pf1b + wB1[w];
        pf1a *= wA1[w];
    }

    // gamma entering each chunk.
    float g0 = x0a * pf0b + x0b;
    float g1 = x1a * (pf1a * tb0 + pf1b) + x1b;

    // ---- Replay: emit sigma, advance gamma. Plain stores (no NT).
    f32x4 sg;
    #pragma unroll
    for (int j = 0; j < 4; ++j) {
        sg[j] = 2.5f * e0[j] - g0;
        g0 = g0 + h0[j] * (e0[j] - g0);
    }
    *(f32x4*)(o_row + i0) = sg;
    #pragma unroll
    for (int j = 0; j < 4; ++j) {
        sg[j] = 2.5f * e0[4 + j] - g0;
        g0 = g0 + h0[4 + j] * (e0[4 + j] - g0);
    }
    *(f32x4*)(o_row + i0 + 4) = sg;
    #pragma unroll
    for (int j = 0; j < 4; ++j) {
        sg[j] = 2.5f * e1[j] - g1;
        g1 = g1 + h1[j] * (e1[j] - g1);
    }
    *(f32x4*)(o_row + i1) = sg;
    #pragma unroll
    for (int j = 0; j < 4; ++j) {
        sg[j] = 2.5f * e1[4 + j] - g1;
        g1 = g1 + h1[4 + j] * (e1[4 + j] - g1);
    }
    *(f32x4*)(o_row + i1 + 4) = sg;
}

extern "C" void kernel_launch(void* const* d_in, const int* in_sizes, int n_in,
                              void* d_out, int out_size, void* d_ws, size_t ws_size,
                              hipStream_t stream) {
    const float* eps = (const float*)d_in[0];
    const float* dtv = (const float*)d_in[1];
    float* out = (float*)d_out;
    const int B = in_sizes[0] / T_LEN;   // 4096 rows
    maxwell_scan_kernel<<<B, THREADS, 0, stream>>>(eps, dtv, out);
}